// Round 14
// baseline (3470.756 us; speedup 1.0000x reference)
//
#include <hip/hip_runtime.h>
#include <hip/hip_bf16.h>

#define TSTEPS 512
#define BATCH  64
#define DIM    512
#define NWG    16

using short8 = __attribute__((ext_vector_type(8))) short;
using f32x4  = __attribute__((ext_vector_type(4))) float;

__device__ __forceinline__ unsigned short f2bf(float f) {
    unsigned u = __builtin_bit_cast(unsigned, f);
    unsigned r = (u + 0x7FFFu + ((u >> 16) & 1u)) >> 16;   // RNE
    return (unsigned short)r;
}

// ---------- fp32 [a][b] -> bf16 [b][a]  (for xh and o) ----------
__global__ void conv_T(const float* __restrict__ src, unsigned short* __restrict__ dst) {
    __shared__ float tile[32][33];
    const int bx = blockIdx.x * 32, by = blockIdx.y * 32;
    const int tx = threadIdx.x & 31, ty = threadIdx.x >> 5;
#pragma unroll
    for (int k = 0; k < 32; k += 8)
        tile[ty + k][tx] = src[(size_t)(by + ty + k) * DIM + bx + tx];
    __syncthreads();
#pragma unroll
    for (int k = 0; k < 32; k += 8)
        dst[(size_t)(bx + ty + k) * DIM + by + tx] = f2bf(tile[tx][ty + k]);
}

// ---------- XW = x @ xh + hb (bf16 MFMA) -> d_out, layout [t][m][kg][col] float4(r) ----------
__global__ __launch_bounds__(256) void gemm_xwm(
    const float* __restrict__ X,            // [32768][512] fp32
    const unsigned short* __restrict__ Bt,  // xhT bf16 [col][k]
    const float* __restrict__ bias, float* __restrict__ Out)
{
    __shared__ unsigned short As[128 * 40];
    __shared__ unsigned short Bs[128 * 40];
    const int tid = threadIdx.x;
    const int m0 = blockIdx.x * 128, n0 = blockIdx.y * 128;
    const int lane = tid & 63, wv = tid >> 6;
    const int ln15 = lane & 15, kg = lane >> 4;
    const int wr = (wv >> 1) * 64, wc = (wv & 1) * 64;

    f32x4 acc[4][4];
#pragma unroll
    for (int m = 0; m < 4; ++m)
#pragma unroll
        for (int n = 0; n < 4; ++n) acc[m][n] = f32x4{0.f, 0.f, 0.f, 0.f};

    const int arow = tid >> 1, ahalf = tid & 1;
    for (int k0 = 0; k0 < DIM; k0 += 32) {
        const float4* ga = reinterpret_cast<const float4*>(
            X + (size_t)(m0 + arow) * DIM + k0 + ahalf * 16);
        float4 a0 = ga[0], a1 = ga[1], a2 = ga[2], a3 = ga[3];
        const ulonglong2* gb = reinterpret_cast<const ulonglong2*>(
            Bt + (size_t)(n0 + arow) * DIM + k0 + ahalf * 16);
        ulonglong2 bv0 = gb[0], bv1 = gb[1];
        __syncthreads();
        {
            unsigned long long p[4];
            const float4 av[4] = {a0, a1, a2, a3};
#pragma unroll
            for (int q = 0; q < 4; ++q)
                p[q] = (unsigned long long)f2bf(av[q].x)
                     | ((unsigned long long)f2bf(av[q].y) << 16)
                     | ((unsigned long long)f2bf(av[q].z) << 32)
                     | ((unsigned long long)f2bf(av[q].w) << 48);
            unsigned long long* s = reinterpret_cast<unsigned long long*>(&As[arow * 40 + ahalf * 16]);
            s[0] = p[0]; s[1] = p[1]; s[2] = p[2]; s[3] = p[3];
            *reinterpret_cast<ulonglong2*>(&Bs[arow * 40 + ahalf * 16]) = bv0;
            *reinterpret_cast<ulonglong2*>(&Bs[arow * 40 + ahalf * 16 + 8]) = bv1;
        }
        __syncthreads();
        short8 af[4], bf[4];
#pragma unroll
        for (int m = 0; m < 4; ++m)
            af[m] = *reinterpret_cast<const short8*>(&As[(wr + m * 16 + ln15) * 40 + kg * 8]);
#pragma unroll
        for (int n = 0; n < 4; ++n)
            bf[n] = *reinterpret_cast<const short8*>(&Bs[(wc + n * 16 + ln15) * 40 + kg * 8]);
#pragma unroll
        for (int m = 0; m < 4; ++m)
#pragma unroll
            for (int n = 0; n < 4; ++n)
                acc[m][n] = __builtin_amdgcn_mfma_f32_16x16x32_bf16(af[m], bf[n], acc[m][n], 0, 0, 0);
    }
    float4* Out4 = reinterpret_cast<float4*>(Out);
#pragma unroll
    for (int n = 0; n < 4; ++n) {
        int col = n0 + wc + n * 16 + ln15;
        float bb = bias[col];
#pragma unroll
        for (int m = 0; m < 4; ++m) {
            int t = (m0 + wr) >> 6;
            float4 v;
            v.x = acc[m][n][0] + bb; v.y = acc[m][n][1] + bb;
            v.z = acc[m][n][2] + bb; v.w = acc[m][n][3] + bb;
            Out4[(((size_t)t * 4 + m) * 4 + kg) * DIM + col] = v;
        }
    }
}

// ---------- persistent scan: 16 WGs x 2 waves, LDS-staged, coalesced sc0sc1 staging ----------
// Wave (wg,w) owns cols [32wg+16w,+16), ALL 64 batch rows (m=0..3). Per step:
//   poll 16 flags (lanes 0-15) -> stage full H (64KB) via 32 coalesced dwordx4/thread,
//   all in flight -> XOR-swizzled LDS -> barrier -> 64 ds_read_b128 + 64 MFMA
//   -> relu -> paired-u32 agent stores -> drain -> barrier -> flag bump -> XW prefetch.
__global__ __launch_bounds__(128, 1) void rnn_scan(
    const float* __restrict__ hh, const float* __restrict__ xwb,
    const float* __restrict__ h0, unsigned short* hist,
    unsigned int* flags)
{
    const int tid  = threadIdx.x;              // 0..127
    const int wg   = blockIdx.x;               // 0..15
    const int lane = tid & 63;
    const int w    = __builtin_amdgcn_readfirstlane(tid >> 6);   // 0..1
    const int ln15 = lane & 15, kg = lane >> 4;
    const int colw = wg * 32 + w * 16 + ln15;
    const int colp = colw >> 1;
    const bool even = (ln15 & 1) == 0;

    __shared__ unsigned long long hsU[8192];   // 64KB H tile, XOR-swizzled
    char* lbase = reinterpret_cast<char*>(hsU);

    // hh columns -> B-fragments (64 VGPR)
    short8 Bhh[16];
#pragma unroll
    for (int kk = 0; kk < 16; ++kk) {
        short8 b;
#pragma unroll
        for (int j = 0; j < 8; ++j)
            b[j] = (short)f2bf(hh[(size_t)(kk * 32 + kg * 8 + j) * DIM + colw]);
        Bhh[kk] = b;
    }

    // prefill hist[0]: all 64 rows x own 16 cols, h0 broadcast over batch
    {
        unsigned* hd32 = reinterpret_cast<unsigned*>(hist);
        unsigned self = f2bf(h0[colw]);
        unsigned partner = (unsigned)__shfl_xor((int)self, 1);
        unsigned pair = even ? (self | (partner << 16)) : (partner | (self << 16));
#pragma unroll
        for (int m = 0; m < 4; ++m)
            if (even == (m < 2)) {
#pragma unroll
                for (int r = 0; r < 4; ++r)
                    __hip_atomic_store(&hd32[(16 * m + kg * 4 + r) * 256 + colp], pair,
                                       __ATOMIC_RELAXED, __HIP_MEMORY_SCOPE_AGENT);
            }
    }
    asm volatile("s_waitcnt vmcnt(0)" ::: "memory");
    __syncthreads();
    if (tid == 0)
        __hip_atomic_store(&flags[wg * 16], 1u,
                           __ATOMIC_RELAXED, __HIP_MEMORY_SCOPE_AGENT);

    const float4* xw4 = reinterpret_cast<const float4*>(xwb);
    f32x4 xw_[4];
#pragma unroll
    for (int m = 0; m < 4; ++m) {
        float4 v = xw4[(((size_t)0 * 4 + m) * 4 + kg) * DIM + colw];
        xw_[m] = f32x4{v.x, v.y, v.z, v.w};
    }

    const int srow = tid >> 1, shalf = tid & 1;    // staging: row, column half

    for (int t = 0; t < TSTEPS; ++t) {
        // ---- poll: all 16 WG flags >= t+1 (lanes 0-15, one line each) ----
        {
            const unsigned target = (unsigned)(t + 1);
            for (;;) {
                unsigned fl = target;
                if (lane < NWG)
                    fl = __hip_atomic_load(&flags[lane * 16],
                                           __ATOMIC_RELAXED, __HIP_MEMORY_SCOPE_AGENT);
                if (!__any(fl < target)) break;
                __builtin_amdgcn_s_sleep(1);
            }
        }

        // ---- stage H_t: 32 coalesced dwordx4/thread, all in flight, then LDS ----
        {
            const unsigned short* src = hist + (size_t)t * (BATCH * DIM)
                                      + (size_t)srow * DIM + shalf * 256;
            short8 v[32];
#pragma unroll
            for (int j = 0; j < 32; ++j)
                asm volatile("global_load_dwordx4 %0, %1, off sc0 sc1"
                             : "=v"(v[j]) : "v"(src + j * 8) : "memory");
            asm volatile("s_waitcnt vmcnt(0)" ::: "memory");
            __builtin_amdgcn_sched_barrier(0);
#pragma unroll
            for (int j = 0; j < 32; ++j) {
                int byte = srow * 1024 + ((shalf * 512 + j * 16) ^ ((srow & 7) << 4));
                *reinterpret_cast<short8*>(lbase + byte) = v[j];
            }
        }
        __syncthreads();

        // ---- 64 ds_read_b128 + 64 MFMA ----
        f32x4 acc[4];
#pragma unroll
        for (int m = 0; m < 4; ++m) acc[m] = f32x4{0.f, 0.f, 0.f, 0.f};
#pragma unroll
        for (int kk = 0; kk < 16; ++kk) {
#pragma unroll
            for (int m = 0; m < 4; ++m) {
                int row = m * 16 + ln15;
                int byte = row * 1024 + ((kk * 64 + kg * 16) ^ ((row & 7) << 4));
                short8 a = *reinterpret_cast<const short8*>(lbase + byte);
                acc[m] = __builtin_amdgcn_mfma_f32_16x16x32_bf16(a, Bhh[kk], acc[m], 0, 0, 0);
            }
        }

        // ---- H_{t+1} = relu(XW + acc) -> hist[t+1] (paired u32 agent stores) ----
        unsigned* hd32 = reinterpret_cast<unsigned*>(hist + (size_t)(t + 1) * (BATCH * DIM));
#pragma unroll
        for (int m = 0; m < 4; ++m) {
            unsigned pr[4];
#pragma unroll
            for (int r = 0; r < 4; ++r) {
                float hn = xw_[m][r] + acc[m][r];
                hn = hn > 0.f ? hn : 0.f;
                unsigned self = f2bf(hn);
                unsigned partner = (unsigned)__shfl_xor((int)self, 1);
                pr[r] = even ? (self | (partner << 16)) : (partner | (self << 16));
            }
            if (even == (m < 2)) {
#pragma unroll
                for (int r = 0; r < 4; ++r)
                    __hip_atomic_store(&hd32[(16 * m + kg * 4 + r) * 256 + colp], pr[r],
                                       __ATOMIC_RELAXED, __HIP_MEMORY_SCOPE_AGENT);
            }
        }
        asm volatile("s_waitcnt vmcnt(0)" ::: "memory");   // H at coherence point
        __syncthreads();                                    // both waves done
        if (t < TSTEPS - 1) {
            if (tid == 0)
                __hip_atomic_store(&flags[wg * 16], (unsigned)(t + 2),
                                   __ATOMIC_RELAXED, __HIP_MEMORY_SCOPE_AGENT);
            // XW prefetch for t+1 (drains during next poll/staging)
#pragma unroll
            for (int m = 0; m < 4; ++m) {
                float4 v = xw4[(((size_t)(t + 1) * 4 + m) * 4 + kg) * DIM + colw];
                xw_[m] = f32x4{v.x, v.y, v.z, v.w};
            }
        }
    }
}

// ---------- Y = Hist(slices 1..512) @ o : MFMA GEMM, 128x128x32 tiles ----------
__global__ __launch_bounds__(256) void gemm_y(
    const unsigned short* __restrict__ A,   // hist + 32768: [32768][512] bf16
    const unsigned short* __restrict__ Bt,  // oT bf16 [col][k]
    float* __restrict__ Out)                // [32768][512] fp32
{
    __shared__ unsigned short As[128 * 40];
    __shared__ unsigned short Bs[128 * 40];
    const int tid = threadIdx.x;
    const int m0 = blockIdx.x * 128, n0 = blockIdx.y * 128;
    const int lane = tid & 63, wv = tid >> 6;
    const int ln15 = lane & 15, kg = lane >> 4;
    const int wr = (wv >> 1) * 64, wc = (wv & 1) * 64;

    f32x4 acc[4][4];
#pragma unroll
    for (int m = 0; m < 4; ++m)
#pragma unroll
        for (int n = 0; n < 4; ++n) acc[m][n] = f32x4{0.f, 0.f, 0.f, 0.f};

    const int sr = tid & 127;
    for (int k0 = 0; k0 < DIM; k0 += 32) {
        const unsigned short* g = (tid < 128)
            ? A  + (size_t)(m0 + sr) * DIM + k0
            : Bt + (size_t)(n0 + sr) * DIM + k0;
        unsigned short* s = (tid < 128) ? &As[sr * 40] : &Bs[sr * 40];
        ulonglong2 v0 = reinterpret_cast<const ulonglong2*>(g)[0];
        ulonglong2 v1 = reinterpret_cast<const ulonglong2*>(g)[1];
        ulonglong2 v2 = reinterpret_cast<const ulonglong2*>(g)[2];
        ulonglong2 v3 = reinterpret_cast<const ulonglong2*>(g)[3];
        __syncthreads();
        reinterpret_cast<ulonglong2*>(s)[0] = v0;
        reinterpret_cast<ulonglong2*>(s)[1] = v1;
        reinterpret_cast<ulonglong2*>(s)[2] = v2;
        reinterpret_cast<ulonglong2*>(s)[3] = v3;
        __syncthreads();
        short8 af[4], bf[4];
#pragma unroll
        for (int m = 0; m < 4; ++m)
            af[m] = *reinterpret_cast<const short8*>(&As[(wr + m * 16 + ln15) * 40 + kg * 8]);
#pragma unroll
        for (int n = 0; n < 4; ++n)
            bf[n] = *reinterpret_cast<const short8*>(&Bs[(wc + n * 16 + ln15) * 40 + kg * 8]);
#pragma unroll
        for (int m = 0; m < 4; ++m)
#pragma unroll
            for (int n = 0; n < 4; ++n)
                acc[m][n] = __builtin_amdgcn_mfma_f32_16x16x32_bf16(af[m], bf[n], acc[m][n], 0, 0, 0);
    }
#pragma unroll
    for (int m = 0; m < 4; ++m)
#pragma unroll
        for (int n = 0; n < 4; ++n)
#pragma unroll
            for (int r = 0; r < 4; ++r) {
                int row = m0 + wr + m * 16 + kg * 4 + r;
                int col = n0 + wc + n * 16 + ln15;
                Out[(size_t)row * DIM + col] = acc[m][n][r];
            }
}

extern "C" void kernel_launch(void* const* d_in, const int* in_sizes, int n_in,
                              void* d_out, int out_size, void* d_ws, size_t ws_size,
                              hipStream_t stream) {
    const float* x  = (const float*)d_in[0];
    const float* xh = (const float*)d_in[1];
    const float* hh = (const float*)d_in[2];
    const float* hb = (const float*)d_in[3];
    const float* o  = (const float*)d_in[4];
    const float* h0 = (const float*)d_in[5];
    float* out = (float*)d_out;

    unsigned int* flags = (unsigned int*)d_ws;                          // 16 x 64B slots
    unsigned short* hist = (unsigned short*)((char*)d_ws + 4096);       // 513 * 64KB
    unsigned short* oT  = (unsigned short*)((char*)d_ws + 4096 + (size_t)513 * 65536);
    unsigned short* xhT = oT + (size_t)DIM * DIM;

    (void)hipMemsetAsync(d_ws, 0, 4096, stream);
    conv_T<<<dim3(16, 16), 256, 0, stream>>>(o, oT);
    conv_T<<<dim3(16, 16), 256, 0, stream>>>(xh, xhT);
    gemm_xwm<<<dim3(256, 4), 256, 0, stream>>>(x, xhT, hb, out);
    rnn_scan<<<NWG, 128, 0, stream>>>(hh, out, h0, hist, flags);
    gemm_y<<<dim3(256, 4), 256, 0, stream>>>(hist + 32768, oT, out);
}

// Round 15
// 2633.540 us; speedup vs baseline: 1.3179x; 1.3179x over previous
//
#include <hip/hip_runtime.h>
#include <hip/hip_bf16.h>

#define TSTEPS 512
#define BATCH  64
#define DIM    512
#define NWG    8

using short8 = __attribute__((ext_vector_type(8))) short;
using f32x4  = __attribute__((ext_vector_type(4))) float;

__device__ __forceinline__ unsigned short f2bf(float f) {
    unsigned u = __builtin_bit_cast(unsigned, f);
    unsigned r = (u + 0x7FFFu + ((u >> 16) & 1u)) >> 16;   // RNE
    return (unsigned short)r;
}

// ---------- fp32 [a][b] -> bf16 [b][a]  (for xh and o) ----------
__global__ void conv_T(const float* __restrict__ src, unsigned short* __restrict__ dst) {
    __shared__ float tile[32][33];
    const int bx = blockIdx.x * 32, by = blockIdx.y * 32;
    const int tx = threadIdx.x & 31, ty = threadIdx.x >> 5;
#pragma unroll
    for (int k = 0; k < 32; k += 8)
        tile[ty + k][tx] = src[(size_t)(by + ty + k) * DIM + bx + tx];
    __syncthreads();
#pragma unroll
    for (int k = 0; k < 32; k += 8)
        dst[(size_t)(bx + ty + k) * DIM + by + tx] = f2bf(tile[tx][ty + k]);
}

// ---------- XW = x @ xh + hb (bf16 MFMA) -> d_out, layout [t][m][kg][col] float4(r) ----------
__global__ __launch_bounds__(256) void gemm_xwm(
    const float* __restrict__ X,            // [32768][512] fp32
    const unsigned short* __restrict__ Bt,  // xhT bf16 [col][k]
    const float* __restrict__ bias, float* __restrict__ Out)
{
    __shared__ unsigned short As[128 * 40];
    __shared__ unsigned short Bs[128 * 40];
    const int tid = threadIdx.x;
    const int m0 = blockIdx.x * 128, n0 = blockIdx.y * 128;
    const int lane = tid & 63, wv = tid >> 6;
    const int ln15 = lane & 15, kg = lane >> 4;
    const int wr = (wv >> 1) * 64, wc = (wv & 1) * 64;

    f32x4 acc[4][4];
#pragma unroll
    for (int m = 0; m < 4; ++m)
#pragma unroll
        for (int n = 0; n < 4; ++n) acc[m][n] = f32x4{0.f, 0.f, 0.f, 0.f};

    const int arow = tid >> 1, ahalf = tid & 1;
    for (int k0 = 0; k0 < DIM; k0 += 32) {
        const float4* ga = reinterpret_cast<const float4*>(
            X + (size_t)(m0 + arow) * DIM + k0 + ahalf * 16);
        float4 a0 = ga[0], a1 = ga[1], a2 = ga[2], a3 = ga[3];
        const ulonglong2* gb = reinterpret_cast<const ulonglong2*>(
            Bt + (size_t)(n0 + arow) * DIM + k0 + ahalf * 16);
        ulonglong2 bv0 = gb[0], bv1 = gb[1];
        __syncthreads();
        {
            unsigned long long p[4];
            const float4 av[4] = {a0, a1, a2, a3};
#pragma unroll
            for (int q = 0; q < 4; ++q)
                p[q] = (unsigned long long)f2bf(av[q].x)
                     | ((unsigned long long)f2bf(av[q].y) << 16)
                     | ((unsigned long long)f2bf(av[q].z) << 32)
                     | ((unsigned long long)f2bf(av[q].w) << 48);
            unsigned long long* s = reinterpret_cast<unsigned long long*>(&As[arow * 40 + ahalf * 16]);
            s[0] = p[0]; s[1] = p[1]; s[2] = p[2]; s[3] = p[3];
            *reinterpret_cast<ulonglong2*>(&Bs[arow * 40 + ahalf * 16]) = bv0;
            *reinterpret_cast<ulonglong2*>(&Bs[arow * 40 + ahalf * 16 + 8]) = bv1;
        }
        __syncthreads();
        short8 af[4], bf[4];
#pragma unroll
        for (int m = 0; m < 4; ++m)
            af[m] = *reinterpret_cast<const short8*>(&As[(wr + m * 16 + ln15) * 40 + kg * 8]);
#pragma unroll
        for (int n = 0; n < 4; ++n)
            bf[n] = *reinterpret_cast<const short8*>(&Bs[(wc + n * 16 + ln15) * 40 + kg * 8]);
#pragma unroll
        for (int m = 0; m < 4; ++m)
#pragma unroll
            for (int n = 0; n < 4; ++n)
                acc[m][n] = __builtin_amdgcn_mfma_f32_16x16x32_bf16(af[m], bf[n], acc[m][n], 0, 0, 0);
    }
    float4* Out4 = reinterpret_cast<float4*>(Out);
#pragma unroll
    for (int n = 0; n < 4; ++n) {
        int col = n0 + wc + n * 16 + ln15;
        float bb = bias[col];
#pragma unroll
        for (int m = 0; m < 4; ++m) {
            int t = (m0 + wr) >> 6;
            float4 v;
            v.x = acc[m][n][0] + bb; v.y = acc[m][n][1] + bb;
            v.z = acc[m][n][2] + bb; v.w = acc[m][n][3] + bb;
            Out4[(((size_t)t * 4 + m) * 4 + kg) * DIM + col] = v;
        }
    }
}

// ---------- persistent scan: flagless tagged-sign dataflow ----------
// All H values >= 0 (relu) -> bf16 sign bit is the validity tag. Producers store
// bf16|0x8000 (agent atomics); consumers load their staging chunks immediately
// (sc0 sc1 raw, coalesced 1KB/instr, all 16 in flight) and retry until every
// chunk's 8 sign bits are set. No flags, no drains, no polls. hist slices are
// write-once (513) -> no reuse race; hist zeroed per launch (memsetAsync).
__global__ __launch_bounds__(256, 1) void rnn_scan(
    const float* __restrict__ hh, const float* __restrict__ xwb,
    const float* __restrict__ h0, unsigned short* hist)
{
    const int tid  = threadIdx.x;
    const int wg   = blockIdx.x;
    const int lane = tid & 63;
    const int wv   = __builtin_amdgcn_readfirstlane(tid >> 6);
    const int ln15 = lane & 15, kg = lane >> 4;
    const int colw = wg * 64 + wv * 16 + ln15;
    const int colp = colw >> 1;
    const bool even = (ln15 & 1) == 0;

    __shared__ unsigned long long hsU[8192];   // 64 KB H tile, XOR-swizzled
    char* lbase = reinterpret_cast<char*>(hsU);

    // hh columns -> B-fragments (64 VGPR)
    short8 Bhh[16];
#pragma unroll
    for (int kk = 0; kk < 16; ++kk) {
        short8 b;
#pragma unroll
        for (int j = 0; j < 8; ++j)
            b[j] = (short)f2bf(hh[(size_t)(kk * 32 + kg * 8 + j) * DIM + colw]);
        Bhh[kk] = b;
    }

    // prefill slice 0 (tagged): own cols x all 64 rows, h0 broadcast over batch
    {
        unsigned* hd32 = reinterpret_cast<unsigned*>(hist);
        unsigned self = (unsigned)f2bf(h0[colw]) | 0x8000u;
        unsigned partner = (unsigned)__shfl_xor((int)self, 1);
        unsigned pair = even ? (self | (partner << 16)) : (partner | (self << 16));
#pragma unroll
        for (int m = 0; m < 4; ++m)
            if (even == (m < 2)) {
#pragma unroll
                for (int r = 0; r < 4; ++r)
                    __hip_atomic_store(&hd32[(16 * m + kg * 4 + r) * 256 + colp], pair,
                                       __ATOMIC_RELAXED, __HIP_MEMORY_SCOPE_AGENT);
            }
    }
    // no drain: consumers validate data directly

    const float4* xw4 = reinterpret_cast<const float4*>(xwb);
    f32x4 xw_[4];
#pragma unroll
    for (int m = 0; m < 4; ++m) {
        float4 v = xw4[(((size_t)0 * 4 + m) * 4 + kg) * DIM + colw];
        xw_[m] = f32x4{v.x, v.y, v.z, v.w};
    }

    for (int t = 0; t < TSTEPS; ++t) {
        // ---- validated staging: 16 coalesced dwordx4/thread, retry until tagged ----
        const short8* src = reinterpret_cast<const short8*>(hist + (size_t)t * (BATCH * DIM));
        short8 v[16];
        for (;;) {
#pragma unroll
            for (int j = 0; j < 16; ++j)
                asm volatile("global_load_dwordx4 %0, %1, off sc0 sc1"
                             : "=v"(v[j]) : "v"(src + j * 256 + tid) : "memory");
            asm volatile("s_waitcnt vmcnt(0)" ::: "memory");
            unsigned all = 0xFFFFFFFFu;
#pragma unroll
            for (int j = 0; j < 16; ++j) {
                uint4 w = __builtin_bit_cast(uint4, v[j]);
                all &= w.x & w.y & w.z & w.w;
            }
            bool ok = ((all & 0x80008000u) == 0x80008000u);
            if (!__any(!ok)) break;
            __builtin_amdgcn_s_sleep(1);
        }
        __syncthreads();   // all waves done reading LDS tile of step t-1

        // ---- strip tags + conflict-free swizzled LDS write (1KB whole-row/instr) ----
#pragma unroll
        for (int j = 0; j < 16; ++j) {
            uint4 w = __builtin_bit_cast(uint4, v[j]);
            w.x &= 0x7FFF7FFFu; w.y &= 0x7FFF7FFFu; w.z &= 0x7FFF7FFFu; w.w &= 0x7FFF7FFFu;
            int i = j * 256 + tid;
            int row = i >> 6, c = i & 63;
            int byte = (row << 10) + ((c << 4) ^ ((row & 7) << 4));
            *reinterpret_cast<short8*>(lbase + byte) = __builtin_bit_cast(short8, w);
        }
        __syncthreads();

        // ---- 64 ds_read_b128 + 64 MFMA ----
        f32x4 acc[4];
#pragma unroll
        for (int m = 0; m < 4; ++m) acc[m] = f32x4{0.f, 0.f, 0.f, 0.f};
#pragma unroll
        for (int kk = 0; kk < 16; ++kk) {
#pragma unroll
            for (int m = 0; m < 4; ++m) {
                int row = m * 16 + ln15;
                int byte = (row << 10) + (((kk << 6) + (kg << 4)) ^ ((row & 7) << 4));
                short8 a = *reinterpret_cast<const short8*>(lbase + byte);
                acc[m] = __builtin_amdgcn_mfma_f32_16x16x32_bf16(a, Bhh[kk], acc[m], 0, 0, 0);
            }
        }

        // ---- H_{t+1} = relu(XW + acc), tagged, -> slice t+1 (no drain, no flag) ----
        unsigned* hd32 = reinterpret_cast<unsigned*>(hist + (size_t)(t + 1) * (BATCH * DIM));
#pragma unroll
        for (int m = 0; m < 4; ++m) {
            unsigned pr[4];
#pragma unroll
            for (int r = 0; r < 4; ++r) {
                float hn = xw_[m][r] + acc[m][r];
                hn = hn > 0.f ? hn : 0.f;
                unsigned self = (unsigned)f2bf(hn) | 0x8000u;
                unsigned partner = (unsigned)__shfl_xor((int)self, 1);
                pr[r] = even ? (self | (partner << 16)) : (partner | (self << 16));
            }
            if (even == (m < 2)) {
#pragma unroll
                for (int r = 0; r < 4; ++r)
                    __hip_atomic_store(&hd32[(16 * m + kg * 4 + r) * 256 + colp], pr[r],
                                       __ATOMIC_RELAXED, __HIP_MEMORY_SCOPE_AGENT);
            }
        }

        if (t < TSTEPS - 1) {
            // XW prefetch for t+1 (drains with next staging vmcnt)
#pragma unroll
            for (int m = 0; m < 4; ++m) {
                float4 vv = xw4[(((size_t)(t + 1) * 4 + m) * 4 + kg) * DIM + colw];
                xw_[m] = f32x4{vv.x, vv.y, vv.z, vv.w};
            }
        }
    }
}

// ---------- Y = Hist(slices 1..512) @ o : MFMA GEMM (strips sign tags on A) ----------
__global__ __launch_bounds__(256) void gemm_y(
    const unsigned short* __restrict__ A,   // hist + 32768: [32768][512] tagged bf16
    const unsigned short* __restrict__ Bt,  // oT bf16 [col][k]
    float* __restrict__ Out)                // [32768][512] fp32
{
    __shared__ unsigned short As[128 * 40];
    __shared__ unsigned short Bs[128 * 40];
    const int tid = threadIdx.x;
    const int m0 = blockIdx.x * 128, n0 = blockIdx.y * 128;
    const int lane = tid & 63, wv = tid >> 6;
    const int ln15 = lane & 15, kg = lane >> 4;
    const int wr = (wv >> 1) * 64, wc = (wv & 1) * 64;

    f32x4 acc[4][4];
#pragma unroll
    for (int m = 0; m < 4; ++m)
#pragma unroll
        for (int n = 0; n < 4; ++n) acc[m][n] = f32x4{0.f, 0.f, 0.f, 0.f};

    const int sr = tid & 127;
    const unsigned long long M = 0x7FFF7FFF7FFF7FFFull;
    for (int k0 = 0; k0 < DIM; k0 += 32) {
        const unsigned short* g = (tid < 128)
            ? A  + (size_t)(m0 + sr) * DIM + k0
            : Bt + (size_t)(n0 + sr) * DIM + k0;
        unsigned short* s = (tid < 128) ? &As[sr * 40] : &Bs[sr * 40];
        ulonglong2 v0 = reinterpret_cast<const ulonglong2*>(g)[0];
        ulonglong2 v1 = reinterpret_cast<const ulonglong2*>(g)[1];
        ulonglong2 v2 = reinterpret_cast<const ulonglong2*>(g)[2];
        ulonglong2 v3 = reinterpret_cast<const ulonglong2*>(g)[3];
        if (tid < 128) {   // strip validity tags from H history
            v0.x &= M; v0.y &= M; v1.x &= M; v1.y &= M;
            v2.x &= M; v2.y &= M; v3.x &= M; v3.y &= M;
        }
        __syncthreads();
        reinterpret_cast<ulonglong2*>(s)[0] = v0;
        reinterpret_cast<ulonglong2*>(s)[1] = v1;
        reinterpret_cast<ulonglong2*>(s)[2] = v2;
        reinterpret_cast<ulonglong2*>(s)[3] = v3;
        __syncthreads();
        short8 af[4], bf[4];
#pragma unroll
        for (int m = 0; m < 4; ++m)
            af[m] = *reinterpret_cast<const short8*>(&As[(wr + m * 16 + ln15) * 40 + kg * 8]);
#pragma unroll
        for (int n = 0; n < 4; ++n)
            bf[n] = *reinterpret_cast<const short8*>(&Bs[(wc + n * 16 + ln15) * 40 + kg * 8]);
#pragma unroll
        for (int m = 0; m < 4; ++m)
#pragma unroll
            for (int n = 0; n < 4; ++n)
                acc[m][n] = __builtin_amdgcn_mfma_f32_16x16x32_bf16(af[m], bf[n], acc[m][n], 0, 0, 0);
    }
#pragma unroll
    for (int m = 0; m < 4; ++m)
#pragma unroll
        for (int n = 0; n < 4; ++n)
#pragma unroll
            for (int r = 0; r < 4; ++r) {
                int row = m0 + wr + m * 16 + kg * 4 + r;
                int col = n0 + wc + n * 16 + ln15;
                Out[(size_t)row * DIM + col] = acc[m][n][r];
            }
}

extern "C" void kernel_launch(void* const* d_in, const int* in_sizes, int n_in,
                              void* d_out, int out_size, void* d_ws, size_t ws_size,
                              hipStream_t stream) {
    const float* x  = (const float*)d_in[0];
    const float* xh = (const float*)d_in[1];
    const float* hh = (const float*)d_in[2];
    const float* hb = (const float*)d_in[3];
    const float* o  = (const float*)d_in[4];
    const float* h0 = (const float*)d_in[5];
    float* out = (float*)d_out;

    unsigned short* hist = (unsigned short*)((char*)d_ws + 4096);       // 513 * 64KB
    unsigned short* oT  = (unsigned short*)((char*)d_ws + 4096 + (size_t)513 * 65536);
    unsigned short* xhT = oT + (size_t)DIM * DIM;

    // zero hist: sign bits are the validity protocol (also kills 0xAA ws poison)
    (void)hipMemsetAsync(d_ws, 0, 4096 + (size_t)513 * 65536, stream);
    conv_T<<<dim3(16, 16), 256, 0, stream>>>(o, oT);
    conv_T<<<dim3(16, 16), 256, 0, stream>>>(xh, xhT);
    gemm_xwm<<<dim3(256, 4), 256, 0, stream>>>(x, xhT, hb, out);
    rnn_scan<<<NWG, 256, 0, stream>>>(hh, out, h0, hist);
    gemm_y<<<dim3(256, 4), 256, 0, stream>>>(hist + 32768, oT, out);
}